// Round 1
// baseline (119.837 us; speedup 1.0000x reference)
//
#include <hip/hip_runtime.h>
#include <hip/hip_cooperative_groups.h>
#include <math.h>

namespace cg = cooperative_groups;

#define N_EXPERTS 64
#define BLOCK 256

// Single cooperative dispatch, no workspace zeroing, no global atomics.
// Phase A: per-block LDS histogram (local rank per token held in registers),
//          unconditional store of the 64 counts to hist[expert][block].
// grid.sync()
// Phase B: base[e] = sum over preceding blocks' hist column (contiguous int4
//          loads, L2-resident), then capacity mask + 16B vectorized writes.
// 256 blocks x 256 threads x 2 tokens/thread = 131072 tokens, 1 block/CU.
__global__ __launch_bounds__(BLOCK) void ExpertCapacityBuffer_80444737454353_kernel(
    const float4* __restrict__ weights,   // (N, 2) float32, one float4 = 2 tokens
    const int4*   __restrict__ experts,   // (N, 2) int32,   one int4   = 2 tokens
    float*        __restrict__ out,       // [0,2N) wc, [2N,4N) idx, [4N,5N) overflow
    int*          __restrict__ hist,      // N_EXPERTS * gridDim.x ints (workspace)
    int N, int capacity)
{
    __shared__ int local_cnt[N_EXPERTS];
    __shared__ int base[N_EXPERTS];

    const int tid = threadIdx.x;
    const int bid = blockIdx.x;
    const int NB  = gridDim.x;

    if (tid < N_EXPERTS) local_cnt[tid] = 0;
    __syncthreads();

    const int P = N >> 1;                 // token pairs
    const int p = bid * BLOCK + tid;      // this thread's pair index
    const bool act = (p < P);

    float4 wv = make_float4(0.f, 0.f, 0.f, 0.f);
    int4   ev = make_int4(0, 0, 0, 0);
    int r0 = 0, r1 = 0, r2 = 0, r3 = 0;

    // Phase A: vector loads + local ranks via LDS atomics
    if (act) {
        wv = weights[p];
        ev = experts[p];
        r0 = atomicAdd(&local_cnt[ev.x], 1);
        r1 = atomicAdd(&local_cnt[ev.y], 1);
        r2 = atomicAdd(&local_cnt[ev.z], 1);
        r3 = atomicAdd(&local_cnt[ev.w], 1);
    }
    __syncthreads();

    // Unconditional publish: every (expert, block) slot written every launch,
    // so the workspace never needs pre-zeroing (harness poison is harmless).
    if (tid < N_EXPERTS) hist[tid * NB + bid] = local_cnt[tid];
    __threadfence();

    cg::this_grid().sync();

    // Phase B: exclusive prefix over preceding blocks for this expert.
    // Column hist[e][0..NB) is contiguous -> int4 loads (NB=256 here).
    if (tid < N_EXPERTS) {
        const int* col = hist + tid * NB;
        int s = 0;
        int j = 0;
        if ((NB & 3) == 0) {                      // 16B-aligned fast path
            const int4* col4 = (const int4*)col;
            const int b4 = bid >> 2;
            #pragma unroll 4
            for (int q = 0; q < b4; ++q) {
                int4 v = col4[q];
                s += v.x + v.y + v.z + v.w;
            }
            j = b4 << 2;
        }
        for (; j < bid; ++j) s += col[j];
        base[tid] = s;
    }
    __syncthreads();

    // Capacity mask + vectorized output writes
    if (act) {
        const float wc0 = (base[ev.x] + r0 < capacity) ? wv.x : 0.0f;
        const float wc1 = (base[ev.y] + r1 < capacity) ? wv.y : 0.0f;
        const float wc2 = (base[ev.z] + r2 < capacity) ? wv.z : 0.0f;
        const float wc3 = (base[ev.w] + r3 < capacity) ? wv.w : 0.0f;

        ((float4*)out)[p] = make_float4(wc0, wc1, wc2, wc3);              // weights_capped
        ((float4*)(out + 2 * (size_t)N))[p] =
            make_float4((float)ev.x, (float)ev.y,
                        (float)ev.z, (float)ev.w);                        // expert_indices
        ((float2*)(out + 4 * (size_t)N))[p] =
            make_float2(((wc0 + wc1) == 0.0f) ? 1.0f : 0.0f,
                        ((wc2 + wc3) == 0.0f) ? 1.0f : 0.0f);             // overflow_mask
    }
}

extern "C" void kernel_launch(void* const* d_in, const int* in_sizes, int n_in,
                              void* d_out, int out_size, void* d_ws, size_t ws_size,
                              hipStream_t stream)
{
    const float4* weights = (const float4*)d_in[0];
    const int4*   experts = (const int4*)d_in[1];
    float*        out     = (float*)d_out;
    int*          hist    = (int*)d_ws;           // N_EXPERTS * blocks ints, NO zeroing needed

    int N = in_sizes[0] / 2;                      // tokens (top_k = 2)
    int capacity = (int)ceil(1.25 * (double)N * 2.0 / (double)N_EXPERTS);
    if (capacity < 1) capacity = 1;

    const int P = N >> 1;                         // token pairs
    int blocks = (P + BLOCK - 1) / BLOCK;         // 256 for N=131072 -> 1 block/CU

    void* args[] = { (void*)&weights, (void*)&experts, (void*)&out, (void*)&hist,
                     (void*)&N, (void*)&capacity };
    hipLaunchCooperativeKernel((const void*)ExpertCapacityBuffer_80444737454353_kernel,
                               dim3(blocks), dim3(BLOCK), args, 0, stream);
}

// Round 2
// 64.482 us; speedup vs baseline: 1.8585x; 1.8585x over previous
//
#include <hip/hip_runtime.h>
#include <math.h>

#define N_EXPERTS 64
#define BLOCK 256

// Two tiny plain dispatches, no workspace zeroing, no global atomics, no grid sync.
//
// Kernel A: per-block LDS histogram of expert ids; unconditionally stores the 64
//           counts to hist[e * NB + b] (column-contiguous per expert). Every slot
//           is written every launch, so harness poison in the workspace is harmless.
// Kernel B: recomputes local ranks via LDS atomics (order-independent counts from
//           A make cross-block bases exact regardless of intra-block atomic order),
//           computes base[e] = sum of preceding blocks' counts via int4 L2 loads,
//           then applies the capacity mask and does 16B-vectorized output writes.
//
// 256 blocks x 256 threads x 2 tokens/thread = 131072 tokens, 1 block/CU.

__global__ __launch_bounds__(BLOCK) void ExpertCapacityBuffer_80444737454353_hist(
    const int4* __restrict__ experts,   // (N, 2) int32, one int4 = 2 tokens
    int*        __restrict__ hist,      // N_EXPERTS * NB ints (workspace, NOT zeroed)
    int P)                              // token pairs
{
    __shared__ int local_cnt[N_EXPERTS];

    const int tid = threadIdx.x;
    const int bid = blockIdx.x;
    const int NB  = gridDim.x;

    if (tid < N_EXPERTS) local_cnt[tid] = 0;
    __syncthreads();

    const int p = bid * BLOCK + tid;
    if (p < P) {
        int4 ev = experts[p];
        atomicAdd(&local_cnt[ev.x], 1);
        atomicAdd(&local_cnt[ev.y], 1);
        atomicAdd(&local_cnt[ev.z], 1);
        atomicAdd(&local_cnt[ev.w], 1);
    }
    __syncthreads();

    // Unconditional publish: every (expert, block) slot written every launch.
    if (tid < N_EXPERTS) hist[tid * NB + bid] = local_cnt[tid];
}

__global__ __launch_bounds__(BLOCK) void ExpertCapacityBuffer_80444737454353_kernel(
    const float4* __restrict__ weights,  // (N, 2) float32, one float4 = 2 tokens
    const int4*   __restrict__ experts,  // (N, 2) int32,   one int4   = 2 tokens
    float*        __restrict__ out,      // [0,2N) wc, [2N,4N) idx, [4N,5N) overflow
    const int*    __restrict__ hist,     // N_EXPERTS * NB ints from kernel A
    int N, int capacity)
{
    __shared__ int local_cnt[N_EXPERTS];
    __shared__ int base[N_EXPERTS];

    const int tid = threadIdx.x;
    const int bid = blockIdx.x;
    const int NB  = gridDim.x;

    if (tid < N_EXPERTS) local_cnt[tid] = 0;
    __syncthreads();

    const int P = N >> 1;                // token pairs
    const int p = bid * BLOCK + tid;
    const bool act = (p < P);

    float4 wv = make_float4(0.f, 0.f, 0.f, 0.f);
    int4   ev = make_int4(0, 0, 0, 0);
    int r0 = 0, r1 = 0, r2 = 0, r3 = 0;

    // Local ranks via LDS atomics (arbitrary intra-block order — counts from A
    // are order-independent, so cross-block bases stay exact).
    if (act) {
        wv = weights[p];
        ev = experts[p];
        r0 = atomicAdd(&local_cnt[ev.x], 1);
        r1 = atomicAdd(&local_cnt[ev.y], 1);
        r2 = atomicAdd(&local_cnt[ev.z], 1);
        r3 = atomicAdd(&local_cnt[ev.w], 1);
    }

    // Exclusive prefix over preceding blocks for this expert. Column
    // hist[e*NB .. e*NB+NB) is contiguous -> int4 loads (L2-resident, 64 KB).
    // Independent of the LDS atomics above, so it overlaps with them.
    if (tid < N_EXPERTS) {
        const int* col = hist + tid * NB;
        int s = 0;
        int j = 0;
        if ((NB & 3) == 0) {                       // 16B-aligned fast path
            const int4* col4 = (const int4*)col;
            const int b4 = bid >> 2;
            #pragma unroll 4
            for (int q = 0; q < b4; ++q) {
                int4 v = col4[q];
                s += v.x + v.y + v.z + v.w;
            }
            j = b4 << 2;
        }
        for (; j < bid; ++j) s += col[j];
        base[tid] = s;
    }
    __syncthreads();

    // Capacity mask + vectorized output writes
    if (act) {
        const float wc0 = (base[ev.x] + r0 < capacity) ? wv.x : 0.0f;
        const float wc1 = (base[ev.y] + r1 < capacity) ? wv.y : 0.0f;
        const float wc2 = (base[ev.z] + r2 < capacity) ? wv.z : 0.0f;
        const float wc3 = (base[ev.w] + r3 < capacity) ? wv.w : 0.0f;

        ((float4*)out)[p] = make_float4(wc0, wc1, wc2, wc3);              // weights_capped
        ((float4*)(out + 2 * (size_t)N))[p] =
            make_float4((float)ev.x, (float)ev.y,
                        (float)ev.z, (float)ev.w);                        // expert_indices
        ((float2*)(out + 4 * (size_t)N))[p] =
            make_float2(((wc0 + wc1) == 0.0f) ? 1.0f : 0.0f,
                        ((wc2 + wc3) == 0.0f) ? 1.0f : 0.0f);             // overflow_mask
    }
}

extern "C" void kernel_launch(void* const* d_in, const int* in_sizes, int n_in,
                              void* d_out, int out_size, void* d_ws, size_t ws_size,
                              hipStream_t stream)
{
    const float4* weights = (const float4*)d_in[0];
    const int4*   experts = (const int4*)d_in[1];
    float*        out     = (float*)d_out;
    int*          hist    = (int*)d_ws;          // N_EXPERTS * blocks ints, NO zeroing needed

    int N = in_sizes[0] / 2;                     // tokens (top_k = 2)
    int capacity = (int)ceil(1.25 * (double)N * 2.0 / (double)N_EXPERTS);
    if (capacity < 1) capacity = 1;

    const int P = N >> 1;                        // token pairs
    const int blocks = (P + BLOCK - 1) / BLOCK;  // 256 for N=131072 -> 1 block/CU

    hipLaunchKernelGGL(ExpertCapacityBuffer_80444737454353_hist,
                       dim3(blocks), dim3(BLOCK), 0, stream,
                       experts, hist, P);
    hipLaunchKernelGGL(ExpertCapacityBuffer_80444737454353_kernel,
                       dim3(blocks), dim3(BLOCK), 0, stream,
                       weights, experts, out, hist, N, capacity);
}